// Round 10
// baseline (118.534 us; speedup 1.0000x reference)
//
#include <hip/hip_runtime.h>
#include <hip/hip_bf16.h>

#define N_NODES 8192
#define DIM 128
#define MASK_THRESH 0.8f
#define ROWS 32
#define RB (N_NODES / ROWS)   // 256 row-blocks
#define KSTEP 64              // k elements per pipeline step

using f32x4  = __attribute__((ext_vector_type(4))) float;
using bf16x8 = __attribute__((ext_vector_type(8))) short;

static __device__ __forceinline__ short f2bf(float f) {
    unsigned u = __builtin_bit_cast(unsigned, f);
    u += 0x7fffu + ((u >> 16) & 1u);
    return (short)(u >> 16);
}

// async global->LDS, 16B/lane; LDS dest = wave-uniform base (+lane*16 implicit)
static __device__ __forceinline__ void gload16(const void* gsrc, void* ldst) {
    __builtin_amdgcn_global_load_lds(
        (const __attribute__((address_space(1))) unsigned int*)gsrc,
        (__attribute__((address_space(3))) unsigned int*)ldst,
        16, 0, 0);
}

// ---------------------------------------------------------------------------
// Kernel 1: V = X@W^T + b stored FRAGMENT-MAJOR as bf16:
//   Vf[((kb*8 + t)*64 + lane)*8 + e] = V[j][d],
//   j = kb*32 + (lane>>4)*8 + e, d = t*16 + (lane&15).   (verified R5-R8)
// ---------------------------------------------------------------------------
__global__ __launch_bounds__(256) void build_vf_kernel(
    const float* __restrict__ X, const float* __restrict__ W,
    const float* __restrict__ bias, short* __restrict__ Vf) {
    __shared__ float xs[32][128];
    const int jt = blockIdx.x * 32;
    for (int e = threadIdx.x; e < 32 * 128; e += 256) {
        xs[e >> 7][e & 127] = X[(size_t)(jt + (e >> 7)) * DIM + (e & 127)];
    }
    __syncthreads();
    const int d  = threadIdx.x & 127;
    const int jh = threadIdx.x >> 7;
    float bv = bias[d];
    float acc[16];
#pragma unroll
    for (int i = 0; i < 16; i++) acc[i] = bv;
    const float* wrow = W + (size_t)d * DIM;
    for (int k = 0; k < DIM; k += 4) {
        f32x4 wv = *(const f32x4*)(wrow + k);
#pragma unroll
        for (int i = 0; i < 16; i++) {
            f32x4 xv = *(const f32x4*)(&xs[jh * 16 + i][k]);
            acc[i] = fmaf(xv[0], wv[0], acc[i]);
            acc[i] = fmaf(xv[1], wv[1], acc[i]);
            acc[i] = fmaf(xv[2], wv[2], acc[i]);
            acc[i] = fmaf(xv[3], wv[3], acc[i]);
        }
    }
    bf16x8 o0, o1;
#pragma unroll
    for (int i = 0; i < 8; i++) { o0[i] = f2bf(acc[i]); o1[i] = f2bf(acc[8 + i]); }
    const int kb = jt >> 5;
    const int t  = d >> 4;
    short* base = Vf + ((size_t)(kb * 8 + t) * 64 + (d & 15) + 32 * jh) * 8;
    *(bf16x8*)(base)       = o0;
    *(bf16x8*)(base + 128) = o1;
}

// ---------------------------------------------------------------------------
// Kernel 2: fused masked-softmax(A) @ V — R8-verified counted-vmcnt skeleton,
//   re-parameterized for 3 blocks/CU.
//   Block: 256 thr (4 waves) = 32 rows x 128 cols. Wave (wr,wc) owns a
//   DISJOINT 16x64 output tile (acc[4]); exp duplicated x2 across wc pair
//   (no cross-wave merge, no LDS overlay). Per KSTEP=64: A[32][64] f32
//   (8KB, ^row&15 swizzled source -> linear LDS -> swizzled ds_read) +
//   Vf slab (16KB contiguous) via global_load_lds, double-buffered. Loop:
//     [s_waitcnt vmcnt(6); s_barrier] compute(ks) [s_barrier] stage(ks+2)
//   Last iteration peeled with vmcnt(0) (no redundant tail re-stage).
// ---------------------------------------------------------------------------
template <int WRITE_PARTIAL>
__global__ __launch_bounds__(256, 3) void fused_kernel(
    const float* __restrict__ A, const short* __restrict__ Vf,
    float* __restrict__ dst, float* __restrict__ Zp, int kchunk, int S) {

    __shared__ __align__(16) float smem_a[2 * 32 * 64];   // 16 KB
    __shared__ __align__(16) short smem_v[2 * 16 * 512];  // 32 KB
    __shared__ float zs2[2][16];                          // separate, no overlay

    const int tid   = threadIdx.x;
    const int wid   = tid >> 6;
    const int lane  = tid & 63;
    const int row_a = lane & 15;
    const int kg    = lane >> 4;
    const int wr    = wid >> 1;          // row half (16 rows)
    const int wc    = wid & 1;           // col half (64 cols)
    const int rb    = blockIdx.x / S;
    const int chunk = blockIdx.x - rb * S;
    const int r0    = rb * ROWS;
    const int k0    = chunk * kchunk;
    const int nsteps = kchunk >> 6;

    // --- A staging: 2 gloads/wave, 4 rows x 256B each, source pre-swizzled ---
    const float* asrcA[2]; int adstA[2];
#pragma unroll
    for (int i = 0; i < 2; i++) {
        const int rowt = wid * 8 + i * 4 + (lane >> 4);
        asrcA[i] = A + (size_t)(r0 + rowt) * N_NODES + k0
                     + (((lane & 15) ^ (rowt & 15)) << 2);
        adstA[i] = (wid * 8 + i * 4) * 64;           // wave-uniform dest base
    }
    // --- V staging: 4 gloads/wave; per step the 16KB frag slab is contiguous ---
    const short* vsrcV = Vf + ((size_t)(k0 >> 5) * 8 + wid * 4) * 512 + lane * 8;
    const int vdst0 = wid * 4 * 512;                 // shorts, wave-uniform

    f32x4 acc[4];
#pragma unroll
    for (int t = 0; t < 4; t++) acc[t] = (f32x4)0.0f;
    float zacc = 0.0f;

    auto stage = [&](int s, int b) {
#pragma unroll
        for (int i = 0; i < 2; i++)
            gload16(asrcA[i] + (size_t)s * KSTEP, smem_a + b * 2048 + adstA[i]);
#pragma unroll
        for (int j = 0; j < 4; j++)
            gload16(vsrcV + (size_t)s * 8192 + j * 512, smem_v + b * 8192 + vdst0 + j * 512);
    };

    auto compute = [&](const float* ab, const short* vb) {
        const int rL = wr * 16 + row_a;
#pragma unroll
        for (int kb = 0; kb < 2; kb++) {
            const int c0 = kb * 8 + kg * 2;
            const f32x4 av0 = *(const f32x4*)(ab + rL * 64 + (((c0 + 0) ^ row_a) << 2));
            const f32x4 av1 = *(const f32x4*)(ab + rL * 64 + (((c0 + 1) ^ row_a) << 2));
            float p[8];
#pragma unroll
            for (int i = 0; i < 4; i++) {
                p[i]     = (av0[i] > MASK_THRESH) ? __expf(av0[i]) : 0.0f;
                p[i + 4] = (av1[i] > MASK_THRESH) ? __expf(av1[i]) : 0.0f;
            }
            bf16x8 af;
#pragma unroll
            for (int i = 0; i < 8; i++) { zacc += p[i]; af[i] = f2bf(p[i]); }
#pragma unroll
            for (int t = 0; t < 4; t++) {
                const bf16x8 bv = *(const bf16x8*)(vb + (kb * 8 + wc * 4 + t) * 512 + lane * 8);
                acc[t] = __builtin_amdgcn_mfma_f32_16x16x32_bf16(af, bv, acc[t], 0, 0, 0);
            }
        }
    };

    // prologue: two batches (6 loads each per wave) in flight
    stage(0, 0);
    stage(1, 1);

    for (int ks = 0; ks < nsteps - 1; ks++) {
        // stage(ks) fully landed; stage(ks+1)'s 6 loads stay outstanding
        asm volatile("s_waitcnt vmcnt(6)\n\ts_barrier" ::: "memory");
        compute(smem_a + (ks & 1) * 2048, smem_v + (ks & 1) * 8192);
        // all waves done reading buf[ks&1]; safe to re-stage it
        asm volatile("s_barrier" ::: "memory");
        if (ks + 2 < nsteps) stage(ks + 2, ks & 1);
    }
    // peeled last step: drain everything, no further staging
    asm volatile("s_waitcnt vmcnt(0)\n\ts_barrier" ::: "memory");
    compute(smem_a + ((nsteps - 1) & 1) * 2048, smem_v + ((nsteps - 1) & 1) * 8192);

    // --- Z: fold 4 kg groups; every lane holds its row_a's chunk-sum ---
    zacc += __shfl_xor(zacc, 16);
    zacc += __shfl_xor(zacc, 32);
    if (wc == 0 && lane < 16) zs2[wr][lane] = zacc;
    __syncthreads();

    if (WRITE_PARTIAL) {
#pragma unroll
        for (int t = 0; t < 4; t++)
#pragma unroll
            for (int r = 0; r < 4; r++) {
                const int rl  = wr * 16 + kg * 4 + r;
                const int col = wc * 64 + t * 16 + row_a;
                dst[((size_t)chunk * N_NODES + r0 + rl) * DIM + col] = acc[t][r];
            }
        if (wc == 0 && lane < 16)
            Zp[(size_t)chunk * N_NODES + r0 + wr * 16 + lane] = zacc;
    } else {
#pragma unroll
        for (int t = 0; t < 4; t++)
#pragma unroll
            for (int r = 0; r < 4; r++) {
                const int rl  = wr * 16 + kg * 4 + r;
                const int col = wc * 64 + t * 16 + row_a;
                const float v = acc[t][r] / zs2[wr][kg * 4 + r];
                dst[(size_t)(r0 + rl) * DIM + col] = (v > 0.0f) ? v : 0.01f * v;
            }
    }
}

// ---------------------------------------------------------------------------
// Kernel 3: sum S partials, normalize, leaky_relu. float4 per thread.
// ---------------------------------------------------------------------------
__global__ __launch_bounds__(256) void reduce_kernel(
    const float* __restrict__ num, const float* __restrict__ Zp,
    float* __restrict__ out, int S) {
    const size_t i4 = (size_t)blockIdx.x * 256 + threadIdx.x;  // quad index
    const int r  = (int)(i4 >> 5);
    const int c4 = (int)(i4 & 31) * 4;
    f32x4 s = (f32x4)0.0f;
    float z = 0.0f;
    for (int p = 0; p < S; p++) {
        s += *(const f32x4*)(num + ((size_t)p * N_NODES + r) * DIM + c4);
        z += Zp[(size_t)p * N_NODES + r];
    }
    f32x4 o;
#pragma unroll
    for (int j = 0; j < 4; j++) {
        const float v = s[j] / z;
        o[j] = (v > 0.0f) ? v : 0.01f * v;
    }
    *(f32x4*)(out + (size_t)r * DIM + c4) = o;
}

extern "C" void kernel_launch(void* const* d_in, const int* in_sizes, int n_in,
                              void* d_out, int out_size, void* d_ws, size_t ws_size,
                              hipStream_t stream) {
    const float* A = (const float*)d_in[0];
    const float* X = (const float*)d_in[1];
    const float* W = (const float*)d_in[2];
    const float* b = (const float*)d_in[3];
    float* out = (float*)d_out;

    const size_t VF_BYTES = (size_t)DIM * N_NODES * 2;   // 2 MiB
    short* Vf = (short*)d_ws;
    build_vf_kernel<<<N_NODES / 32, 256, 0, stream>>>(X, W, b, Vf);

    const size_t per_split = ((size_t)N_NODES * DIM + N_NODES) * sizeof(float);
    int S = 1;
    for (int cand = 8; cand >= 1; cand >>= 1) {
        if (VF_BYTES + (size_t)cand * per_split <= ws_size) { S = cand; break; }
    }

    if (S >= 2) {
        float* num = (float*)((char*)d_ws + VF_BYTES);
        float* Zp  = num + (size_t)S * N_NODES * DIM;
        fused_kernel<1><<<RB * S, 256, 0, stream>>>(A, Vf, num, Zp, N_NODES / S, S);
        reduce_kernel<<<(N_NODES * DIM / 4) / 256, 256, 0, stream>>>(num, Zp, out, S);
    } else {
        fused_kernel<0><<<RB, 256, 0, stream>>>(A, Vf, out, nullptr, N_NODES, 1);
    }
}